// Round 1
// baseline (163.305 us; speedup 1.0000x reference)
//
#include <hip/hip_runtime.h>
#include <hip/hip_bf16.h>

// ---- types ----
typedef _Float16 halfx8 __attribute__((ext_vector_type(8)));
typedef _Float16 halfx4 __attribute__((ext_vector_type(4)));
typedef float floatx4 __attribute__((ext_vector_type(4)));

#define GLOBAL_AS __attribute__((address_space(1)))
#define LDS_AS __attribute__((address_space(3)))

// async global->LDS, 16B per lane; LDS dest = wave-uniform base + lane*16
__device__ __forceinline__ void async_copy_16(const _Float16* g, _Float16* l) {
    __builtin_amdgcn_global_load_lds((GLOBAL_AS void*)g, (LDS_AS void*)l, 16, 0, 0);
}

// problem dims
#define PM 16384
#define PD 768
#define PA 51
#define PA_PAD 64

// ------------------- convert x: fp32 -> fp16, vectorized -------------------
__global__ void convert_x_kernel(const float* __restrict__ src, _Float16* __restrict__ dst) {
    int idx = blockIdx.x * 256 + threadIdx.x;   // over PM*PD/4 = 3145728
    float4 v = ((const float4*)src)[idx];
    halfx4 h;
    h[0] = (_Float16)v.x; h[1] = (_Float16)v.y; h[2] = (_Float16)v.z; h[3] = (_Float16)v.w;
    *(halfx4*)(dst + (size_t)idx * 4) = h;
}

// ------------- convert weights (W_embed, W_attr padded), zero stats -------------
__global__ void convert_w_kernel(const float* __restrict__ We, const float* __restrict__ Wa,
                                 _Float16* __restrict__ we16, _Float16* __restrict__ wa16,
                                 float* __restrict__ stats) {
    int b = blockIdx.x, t = threadIdx.x;
    if (b < 576) {                       // W_embed: 768*768/4 = 147456 float4s
        int idx = b * 256 + t;
        float4 v = ((const float4*)We)[idx];
        halfx4 h;
        h[0] = (_Float16)v.x; h[1] = (_Float16)v.y; h[2] = (_Float16)v.z; h[3] = (_Float16)v.w;
        *(halfx4*)(we16 + (size_t)idx * 4) = h;
    } else if (b < 624) {                // W_attr padded to [64][768]: 12288 groups of 4
        int j = (b - 576) * 256 + t;
        halfx4 h;
        if (j < (PA * PD) / 4) {         // rows < 51: same flat layout as source
            float4 v = ((const float4*)Wa)[j];
            h[0] = (_Float16)v.x; h[1] = (_Float16)v.y; h[2] = (_Float16)v.z; h[3] = (_Float16)v.w;
        } else {
            h[0] = (_Float16)0.f; h[1] = (_Float16)0.f; h[2] = (_Float16)0.f; h[3] = (_Float16)0.f;
        }
        *(halfx4*)(wa16 + (size_t)j * 4) = h;
    } else {
        if (t < 128) stats[t] = 0.f;
    }
}

// ------------------- GEMM1: H = x @ We^T + b_embed  (fp16 out) -------------------
// m97 structure: 128x128 tile, BK=64, 256 threads (2x2 waves of 64x64),
// global_load_lds 16B staging, 16x16x32 f16 MFMA.
__global__ __launch_bounds__(256) void gemm1_kernel(
    const _Float16* __restrict__ A,   // [16384][768] x_f16
    const _Float16* __restrict__ B,   // [768][768]   we16 (row-major = W_embed, NT gemm)
    const float* __restrict__ bias,   // [768] b_embed
    _Float16* __restrict__ H)         // [16384][768]
{
    __shared__ _Float16 As[128 * 64];
    __shared__ _Float16 Bs[128 * 64];
    const int tid = threadIdx.x;
    const int wave = tid >> 6;
    const int lane = tid & 63;
    const int quad = lane >> 4;
    const int l16 = lane & 15;
    const int wm = wave >> 1;
    const int wn = wave & 1;

    // XCD-aware swizzle: 768 blocks; xcd = b%8 owns 16 consecutive M-tiles so the
    // 6 N-tiles sharing an A-stripe hit the same XCD's L2 (heuristic, perf-only).
    int b = blockIdx.x;
    int xcd = b & 7;
    int q = b >> 3;                 // 0..95
    int mt = xcd * 16 + (q & 15);   // 0..127
    int nt = q >> 4;                // 0..5
    const int row0 = mt * 128;
    const int col0 = nt * 128;

    const int r_in = lane >> 3;         // 0..7  (row within 8-row staging group)
    const int koff = (lane & 7) * 8;    // half-elem offset within 64-elem K-chunk

    const _Float16* Ag = A + (size_t)row0 * PD + koff;
    const _Float16* Bg = B + (size_t)col0 * PD + koff;

    floatx4 acc[4][4];
    #pragma unroll
    for (int i = 0; i < 4; ++i)
        #pragma unroll
        for (int j = 0; j < 4; ++j)
            acc[i][j] = (floatx4){0.f, 0.f, 0.f, 0.f};

    for (int kt = 0; kt < PD; kt += 64) {
        #pragma unroll
        for (int j = 0; j < 4; ++j) {
            int i = wave * 4 + j;       // 0..15, covers rows i*8..i*8+7
            async_copy_16(Ag + (size_t)(i * 8 + r_in) * PD + kt, &As[i * 512]);
            async_copy_16(Bg + (size_t)(i * 8 + r_in) * PD + kt, &Bs[i * 512]);
        }
        __syncthreads();
        #pragma unroll
        for (int ks = 0; ks < 2; ++ks) {
            halfx8 af[4], bf[4];
            #pragma unroll
            for (int mi = 0; mi < 4; ++mi)
                af[mi] = *(const halfx8*)&As[(wm * 64 + mi * 16 + l16) * 64 + ks * 32 + quad * 8];
            #pragma unroll
            for (int ni = 0; ni < 4; ++ni)
                bf[ni] = *(const halfx8*)&Bs[(wn * 64 + ni * 16 + l16) * 64 + ks * 32 + quad * 8];
            #pragma unroll
            for (int mi = 0; mi < 4; ++mi)
                #pragma unroll
                for (int ni = 0; ni < 4; ++ni)
                    acc[mi][ni] = __builtin_amdgcn_mfma_f32_16x16x32_f16(af[mi], bf[ni], acc[mi][ni], 0, 0, 0);
        }
        __syncthreads();
    }

    // epilogue: C/D layout col=lane&15, row=quad*4+reg (m89-verified)
    #pragma unroll
    for (int ni = 0; ni < 4; ++ni) {
        int col = col0 + wn * 64 + ni * 16 + l16;
        float bv = bias[col];
        #pragma unroll
        for (int mi = 0; mi < 4; ++mi) {
            int rowb = row0 + wm * 64 + mi * 16 + quad * 4;
            #pragma unroll
            for (int r = 0; r < 4; ++r)
                H[(size_t)(rowb + r) * PD + col] = (_Float16)(acc[mi][ni][r] + bv);
        }
    }
}

// ------- GEMM2: logits = H @ Wa^T + b_attr; also per-col sum/sumsq atomics -------
// 128 rows x 64 cols per block, BK=64, 4 waves each 32x64 (2x4 frags).
__global__ __launch_bounds__(256) void gemm2_kernel(
    const _Float16* __restrict__ Hm,   // [16384][768]
    const _Float16* __restrict__ Wa,   // [64][768] padded
    const float* __restrict__ b_attr,  // [51]
    float* __restrict__ logits,        // [16384][51]
    float* __restrict__ stats)         // [0..50]=sum, [64..114]=sumsq
{
    __shared__ _Float16 As[128 * 64];
    __shared__ _Float16 Bs[64 * 64];
    __shared__ float s_sum[64];
    __shared__ float s_ssq[64];
    const int tid = threadIdx.x;
    const int wave = tid >> 6;
    const int lane = tid & 63;
    const int quad = lane >> 4;
    const int l16 = lane & 15;
    const int row0 = blockIdx.x * 128;
    const int r_in = lane >> 3;
    const int koff = (lane & 7) * 8;

    if (tid < 64) { s_sum[tid] = 0.f; s_ssq[tid] = 0.f; }

    const _Float16* Ag = Hm + (size_t)row0 * PD + koff;
    const _Float16* Bg = Wa + koff;

    floatx4 acc[2][4];
    #pragma unroll
    for (int i = 0; i < 2; ++i)
        #pragma unroll
        for (int j = 0; j < 4; ++j)
            acc[i][j] = (floatx4){0.f, 0.f, 0.f, 0.f};

    for (int kt = 0; kt < PD; kt += 64) {
        #pragma unroll
        for (int j = 0; j < 4; ++j) {
            int i = wave * 4 + j;       // 0..15 -> A rows 0..127
            async_copy_16(Ag + (size_t)(i * 8 + r_in) * PD + kt, &As[i * 512]);
        }
        #pragma unroll
        for (int j = 0; j < 2; ++j) {
            int i = wave * 2 + j;       // 0..7 -> B rows 0..63
            async_copy_16(Bg + (size_t)(i * 8 + r_in) * PD + kt, &Bs[i * 512]);
        }
        __syncthreads();
        #pragma unroll
        for (int ks = 0; ks < 2; ++ks) {
            halfx8 af[2], bf[4];
            #pragma unroll
            for (int mi = 0; mi < 2; ++mi)
                af[mi] = *(const halfx8*)&As[(wave * 32 + mi * 16 + l16) * 64 + ks * 32 + quad * 8];
            #pragma unroll
            for (int ni = 0; ni < 4; ++ni)
                bf[ni] = *(const halfx8*)&Bs[(ni * 16 + l16) * 64 + ks * 32 + quad * 8];
            #pragma unroll
            for (int mi = 0; mi < 2; ++mi)
                #pragma unroll
                for (int ni = 0; ni < 4; ++ni)
                    acc[mi][ni] = __builtin_amdgcn_mfma_f32_16x16x32_f16(af[mi], bf[ni], acc[mi][ni], 0, 0, 0);
        }
        __syncthreads();
    }

    #pragma unroll
    for (int ni = 0; ni < 4; ++ni) {
        int col = ni * 16 + l16;
        if (col < PA) {
            float bv = b_attr[col];
            float ps = 0.f, pss = 0.f;
            #pragma unroll
            for (int mi = 0; mi < 2; ++mi) {
                int rowb = row0 + wave * 32 + mi * 16 + quad * 4;
                #pragma unroll
                for (int r = 0; r < 4; ++r) {
                    float v = acc[mi][ni][r] + bv;
                    logits[(size_t)(rowb + r) * PA + col] = v;
                    ps += v; pss += v * v;
                }
            }
            atomicAdd(&s_sum[col], ps);
            atomicAdd(&s_ssq[col], pss);
        }
    }
    __syncthreads();
    if (tid < PA) {
        atomicAdd(&stats[tid], s_sum[tid]);
        atomicAdd(&stats[64 + tid], s_ssq[tid]);
    }
}

// ------------------- BN finalize -------------------
__global__ void bn_finalize_kernel(const float* __restrict__ logits,
                                   const float* __restrict__ stats,
                                   const float* __restrict__ gamma,
                                   const float* __restrict__ beta,
                                   float* __restrict__ out, int total) {
    __shared__ float s_scale[PA];
    __shared__ float s_shift[PA];
    int t = threadIdx.x;
    if (t < PA) {
        const float invB = 1.0f / (float)PM;
        float mean = stats[t] * invB;
        float var = stats[64 + t] * invB - mean * mean;
        float inv = rsqrtf(var + 1e-5f);
        float g = gamma[t] * inv;
        s_scale[t] = g;
        s_shift[t] = beta[t] - mean * g;
    }
    __syncthreads();
    int idx = blockIdx.x * 256 + t;
    if (idx < total) {
        int col = idx % PA;
        out[idx] = logits[idx] * s_scale[col] + s_shift[col];
    }
}

// ------------------- launch -------------------
extern "C" void kernel_launch(void* const* d_in, const int* in_sizes, int n_in,
                              void* d_out, int out_size, void* d_ws, size_t ws_size,
                              hipStream_t stream) {
    const float* x       = (const float*)d_in[0];
    const float* W_embed = (const float*)d_in[1];
    const float* b_embed = (const float*)d_in[2];
    const float* W_attr  = (const float*)d_in[3];
    const float* b_attr  = (const float*)d_in[4];
    const float* gamma   = (const float*)d_in[5];
    const float* beta    = (const float*)d_in[6];
    float* out = (float*)d_out;

    char* ws = (char*)d_ws;
    _Float16* x_f16  = (_Float16*)(ws);                    // 16384*768*2 = 25165824
    _Float16* we16   = (_Float16*)(ws + 25165824);         // 768*768*2   = 1179648
    _Float16* wa16   = (_Float16*)(ws + 26345472);         // 64*768*2    = 98304
    _Float16* h_f16  = (_Float16*)(ws + 26443776);         // 16384*768*2 = 25165824
    float*    logits = (float*)   (ws + 51609600);         // 16384*51*4  = 3342336
    float*    stats  = (float*)   (ws + 54951936);         // 128*4       = 512

    convert_x_kernel<<<12288, 256, 0, stream>>>(x, x_f16);
    convert_w_kernel<<<625, 256, 0, stream>>>(W_embed, W_attr, we16, wa16, stats);
    gemm1_kernel<<<768, 256, 0, stream>>>(x_f16, we16, b_embed, h_f16);
    gemm2_kernel<<<128, 256, 0, stream>>>(h_f16, wa16, b_attr, logits, stats);
    bn_finalize_kernel<<<3264, 256, 0, stream>>>(logits, stats, gamma, beta, out, PM * PA);
}

// Round 2
// 153.331 us; speedup vs baseline: 1.0651x; 1.0651x over previous
//
#include <hip/hip_runtime.h>
#include <hip/hip_bf16.h>

// ---- types ----
typedef _Float16 halfx8 __attribute__((ext_vector_type(8)));
typedef _Float16 halfx4 __attribute__((ext_vector_type(4)));
typedef float floatx4 __attribute__((ext_vector_type(4)));

#define GLOBAL_AS __attribute__((address_space(1)))
#define LDS_AS __attribute__((address_space(3)))

// async global->LDS, 16B per lane; LDS dest = wave-uniform base + lane*16
__device__ __forceinline__ void async_copy_16(const _Float16* g, _Float16* l) {
    __builtin_amdgcn_global_load_lds((GLOBAL_AS void*)g, (LDS_AS void*)l, 16, 0, 0);
}

// problem dims
#define PM 16384
#define PD 768
#define PA 51
#define PA_PAD 64

// LDS swizzle scheme (bank-conflict fix):
//   Staging: lane l of an 8-row group loads global (row = g*8 + (l>>3),
//   kchunk = (l&7) ^ (l>>3)), so LDS[row][c'] holds global kchunk c' ^ (row&7).
//   Frag read at (row, kc) uses c' = kc ^ (row&7); since row&7 = l16&7 varies
//   across lanes, the 64 lanes of one ds_read_b128 spread uniformly over all 8
//   bank groups (8-way = b128 floor) instead of 16-way on 4 groups.

// ------------- fused converts: x->fp16, We->fp16, Wa(padded)->fp16, zero stats -------------
__global__ void convert_all_kernel(const float* __restrict__ x, const float* __restrict__ We,
                                   const float* __restrict__ Wa,
                                   _Float16* __restrict__ x16, _Float16* __restrict__ we16,
                                   _Float16* __restrict__ wa16, float* __restrict__ stats) {
    int b = blockIdx.x, t = threadIdx.x;
    if (b < 12288) {                     // x: 16384*768/4 = 3145728 float4s
        int idx = b * 256 + t;
        float4 v = ((const float4*)x)[idx];
        halfx4 h;
        h[0] = (_Float16)v.x; h[1] = (_Float16)v.y; h[2] = (_Float16)v.z; h[3] = (_Float16)v.w;
        *(halfx4*)(x16 + (size_t)idx * 4) = h;
    } else if (b < 12288 + 576) {        // W_embed: 768*768/4 = 147456 float4s
        int idx = (b - 12288) * 256 + t;
        float4 v = ((const float4*)We)[idx];
        halfx4 h;
        h[0] = (_Float16)v.x; h[1] = (_Float16)v.y; h[2] = (_Float16)v.z; h[3] = (_Float16)v.w;
        *(halfx4*)(we16 + (size_t)idx * 4) = h;
    } else if (b < 12288 + 624) {        // W_attr padded to [64][768]
        int j = (b - 12288 - 576) * 256 + t;
        halfx4 h;
        if (j < (PA * PD) / 4) {
            float4 v = ((const float4*)Wa)[j];
            h[0] = (_Float16)v.x; h[1] = (_Float16)v.y; h[2] = (_Float16)v.z; h[3] = (_Float16)v.w;
        } else {
            h[0] = (_Float16)0.f; h[1] = (_Float16)0.f; h[2] = (_Float16)0.f; h[3] = (_Float16)0.f;
        }
        *(halfx4*)(wa16 + (size_t)j * 4) = h;
    } else {
        if (t < 128) stats[t] = 0.f;
    }
}

// ------------------- GEMM1: H = x @ We^T + b_embed  (fp16 out) -------------------
// 128x128 tile, BK=64, 256 threads (2x2 waves of 64x64), swizzled LDS.
__global__ __launch_bounds__(256) void gemm1_kernel(
    const _Float16* __restrict__ A,   // [16384][768] x_f16
    const _Float16* __restrict__ B,   // [768][768]   we16
    const float* __restrict__ bias,   // [768] b_embed
    _Float16* __restrict__ H)         // [16384][768]
{
    __shared__ _Float16 As[128 * 64];
    __shared__ _Float16 Bs[128 * 64];
    const int tid = threadIdx.x;
    const int wave = tid >> 6;
    const int lane = tid & 63;
    const int quad = lane >> 4;
    const int l16 = lane & 15;
    const int wm = wave >> 1;
    const int wn = wave & 1;

    // XCD-aware swizzle (perf heuristic only)
    int b = blockIdx.x;
    int xcd = b & 7;
    int q = b >> 3;                 // 0..95
    int mt = xcd * 16 + (q & 15);   // 0..127
    int nt = q >> 4;                // 0..5
    const int row0 = mt * 128;
    const int col0 = nt * 128;

    const int r_in = lane >> 3;                 // 0..7 row within staging group
    const int ksw = ((lane & 7) ^ r_in) * 8;    // swizzled k-offset (half elems)

    const _Float16* Ag = A + (size_t)row0 * PD + ksw;
    const _Float16* Bg = B + (size_t)col0 * PD + ksw;

    floatx4 acc[4][4];
    #pragma unroll
    for (int i = 0; i < 4; ++i)
        #pragma unroll
        for (int j = 0; j < 4; ++j)
            acc[i][j] = (floatx4){0.f, 0.f, 0.f, 0.f};

    for (int kt = 0; kt < PD; kt += 64) {
        #pragma unroll
        for (int j = 0; j < 4; ++j) {
            int i = wave * 4 + j;       // 0..15, rows i*8..i*8+7
            async_copy_16(Ag + (size_t)(i * 8 + r_in) * PD + kt, &As[i * 512]);
            async_copy_16(Bg + (size_t)(i * 8 + r_in) * PD + kt, &Bs[i * 512]);
        }
        __syncthreads();
        #pragma unroll
        for (int ks = 0; ks < 2; ++ks) {
            halfx8 af[4], bf[4];
            #pragma unroll
            for (int mi = 0; mi < 4; ++mi)
                af[mi] = *(const halfx8*)&As[(wm * 64 + mi * 16 + l16) * 64 +
                                             (((ks * 4 + quad) ^ (l16 & 7)) << 3)];
            #pragma unroll
            for (int ni = 0; ni < 4; ++ni)
                bf[ni] = *(const halfx8*)&Bs[(wn * 64 + ni * 16 + l16) * 64 +
                                             (((ks * 4 + quad) ^ (l16 & 7)) << 3)];
            #pragma unroll
            for (int mi = 0; mi < 4; ++mi)
                #pragma unroll
                for (int ni = 0; ni < 4; ++ni)
                    acc[mi][ni] = __builtin_amdgcn_mfma_f32_16x16x32_f16(af[mi], bf[ni], acc[mi][ni], 0, 0, 0);
        }
        __syncthreads();
    }

    // epilogue: C/D layout col=lane&15, row=quad*4+reg (m89-verified)
    #pragma unroll
    for (int ni = 0; ni < 4; ++ni) {
        int col = col0 + wn * 64 + ni * 16 + l16;
        float bv = bias[col];
        #pragma unroll
        for (int mi = 0; mi < 4; ++mi) {
            int rowb = row0 + wm * 64 + mi * 16 + quad * 4;
            #pragma unroll
            for (int r = 0; r < 4; ++r)
                H[(size_t)(rowb + r) * PD + col] = (_Float16)(acc[mi][ni][r] + bv);
        }
    }
}

// ------- GEMM2: logits = H @ Wa^T + b_attr; per-col sum/sumsq atomics -------
// 64 rows x 64 cols per block -> 256 blocks (1/CU). 4 waves, each 16x64.
__global__ __launch_bounds__(256) void gemm2_kernel(
    const _Float16* __restrict__ Hm,   // [16384][768]
    const _Float16* __restrict__ Wa,   // [64][768] padded
    const float* __restrict__ b_attr,  // [51]
    float* __restrict__ logits,        // [16384][51]
    float* __restrict__ stats)         // [0..50]=sum, [64..114]=sumsq
{
    __shared__ _Float16 As[64 * 64];
    __shared__ _Float16 Bs[64 * 64];
    __shared__ float s_sum[64];
    __shared__ float s_ssq[64];
    const int tid = threadIdx.x;
    const int wave = tid >> 6;
    const int lane = tid & 63;
    const int quad = lane >> 4;
    const int l16 = lane & 15;
    const int row0 = blockIdx.x * 64;
    const int r_in = lane >> 3;
    const int ksw = ((lane & 7) ^ r_in) * 8;

    if (tid < 64) { s_sum[tid] = 0.f; s_ssq[tid] = 0.f; }

    const _Float16* Ag = Hm + (size_t)row0 * PD + ksw;
    const _Float16* Bg = Wa + ksw;

    floatx4 acc[4];
    #pragma unroll
    for (int j = 0; j < 4; ++j)
        acc[j] = (floatx4){0.f, 0.f, 0.f, 0.f};

    for (int kt = 0; kt < PD; kt += 64) {
        #pragma unroll
        for (int j = 0; j < 2; ++j) {
            int i = wave * 2 + j;       // 0..7 -> A rows 0..63
            async_copy_16(Ag + (size_t)(i * 8 + r_in) * PD + kt, &As[i * 512]);
        }
        #pragma unroll
        for (int j = 0; j < 2; ++j) {
            int i = wave * 2 + j;       // 0..7 -> B rows 0..63
            async_copy_16(Bg + (size_t)(i * 8 + r_in) * PD + kt, &Bs[i * 512]);
        }
        __syncthreads();
        #pragma unroll
        for (int ks = 0; ks < 2; ++ks) {
            halfx8 af, bf[4];
            af = *(const halfx8*)&As[(wave * 16 + l16) * 64 +
                                     (((ks * 4 + quad) ^ (l16 & 7)) << 3)];
            #pragma unroll
            for (int ni = 0; ni < 4; ++ni)
                bf[ni] = *(const halfx8*)&Bs[(ni * 16 + l16) * 64 +
                                             (((ks * 4 + quad) ^ (l16 & 7)) << 3)];
            #pragma unroll
            for (int ni = 0; ni < 4; ++ni)
                acc[ni] = __builtin_amdgcn_mfma_f32_16x16x32_f16(af, bf[ni], acc[ni], 0, 0, 0);
        }
        __syncthreads();
    }

    #pragma unroll
    for (int ni = 0; ni < 4; ++ni) {
        int col = ni * 16 + l16;
        if (col < PA) {
            float bv = b_attr[col];
            float ps = 0.f, pss = 0.f;
            int rowb = row0 + wave * 16 + quad * 4;
            #pragma unroll
            for (int r = 0; r < 4; ++r) {
                float v = acc[ni][r] + bv;
                logits[(size_t)(rowb + r) * PA + col] = v;
                ps += v; pss += v * v;
            }
            atomicAdd(&s_sum[col], ps);
            atomicAdd(&s_ssq[col], pss);
        }
    }
    __syncthreads();
    if (tid < PA) {
        atomicAdd(&stats[tid], s_sum[tid]);
        atomicAdd(&stats[64 + tid], s_ssq[tid]);
    }
}

// ------------------- BN finalize -------------------
__global__ void bn_finalize_kernel(const float* __restrict__ logits,
                                   const float* __restrict__ stats,
                                   const float* __restrict__ gamma,
                                   const float* __restrict__ beta,
                                   float* __restrict__ out, int total) {
    __shared__ float s_scale[PA];
    __shared__ float s_shift[PA];
    int t = threadIdx.x;
    if (t < PA) {
        const float invB = 1.0f / (float)PM;
        float mean = stats[t] * invB;
        float var = stats[64 + t] * invB - mean * mean;
        float inv = rsqrtf(var + 1e-5f);
        float g = gamma[t] * inv;
        s_scale[t] = g;
        s_shift[t] = beta[t] - mean * g;
    }
    __syncthreads();
    int idx = blockIdx.x * 256 + t;
    if (idx < total) {
        int col = idx % PA;
        out[idx] = logits[idx] * s_scale[col] + s_shift[col];
    }
}

// ------------------- launch -------------------
extern "C" void kernel_launch(void* const* d_in, const int* in_sizes, int n_in,
                              void* d_out, int out_size, void* d_ws, size_t ws_size,
                              hipStream_t stream) {
    const float* x       = (const float*)d_in[0];
    const float* W_embed = (const float*)d_in[1];
    const float* b_embed = (const float*)d_in[2];
    const float* W_attr  = (const float*)d_in[3];
    const float* b_attr  = (const float*)d_in[4];
    const float* gamma   = (const float*)d_in[5];
    const float* beta    = (const float*)d_in[6];
    float* out = (float*)d_out;

    char* ws = (char*)d_ws;
    _Float16* x_f16  = (_Float16*)(ws);                    // 16384*768*2 = 25165824
    _Float16* we16   = (_Float16*)(ws + 25165824);         // 768*768*2   = 1179648
    _Float16* wa16   = (_Float16*)(ws + 26345472);         // 64*768*2    = 98304
    _Float16* h_f16  = (_Float16*)(ws + 26443776);         // 16384*768*2 = 25165824
    float*    logits = (float*)   (ws + 51609600);         // 16384*51*4  = 3342336
    float*    stats  = (float*)   (ws + 54951936);         // 128*4       = 512

    convert_all_kernel<<<12913, 256, 0, stream>>>(x, W_embed, W_attr, x_f16, we16, wa16, stats);
    gemm1_kernel<<<768, 256, 0, stream>>>(x_f16, we16, b_embed, h_f16);
    gemm2_kernel<<<256, 256, 0, stream>>>(h_f16, wa16, b_attr, logits, stats);
    bn_finalize_kernel<<<3264, 256, 0, stream>>>(logits, stats, gamma, beta, out, PM * PA);
}